// Round 7
// baseline (365.145 us; speedup 1.0000x reference)
//
#include <hip/hip_runtime.h>
#include <hip/hip_bf16.h>
#include <cstdint>
#include <cstddef>

// Problem constants (fixed by the reference)
#define TDIM 1024
#define HDIM 1024
#define FDIM 2048
#define NEXP 8
#define NENT 2048   // T * K

typedef __bf16 bf16_t;
typedef __bf16 bf16x4 __attribute__((ext_vector_type(4)));
typedef __bf16 bf16x8 __attribute__((ext_vector_type(8)));
typedef float  f32x4  __attribute__((ext_vector_type(4)));

#define H_ELEMS  ((size_t)TDIM*HDIM)            // 1048576
#define W1_ELEMS ((size_t)NEXP*2*FDIM*HDIM)     // 33554432
#define W2_ELEMS ((size_t)NEXP*HDIM*FDIM)       // 16777216

// ---------------- workspace layout (bytes) ----------------
#define WB_OFFSETS 0                                   // int[16]
#define WB_ETOK    64
#define WB_ESCALE  (WB_ETOK + NENT*4)
#define WB_ACT     16512                               // bf16[NENT][FDIM] = 8 MB
#define WB_H       (WB_ACT + (size_t)NENT*FDIM*2)      // bf16[T][H] = 2 MB
#define WB_W2BF    (WB_H + H_ELEMS*2)                  // bf16 w2r = 32 MB
#define WB_W1BF    (WB_W2BF + W2_ELEMS*2)              // bf16 w1r = 64 MB
#define WB_NEED    (WB_W1BF + W1_ELEMS*2)              // ~106 MB total

__device__ __forceinline__ void gload16(const void* g, void* l) {
  __builtin_amdgcn_global_load_lds((const __attribute__((address_space(1))) void*)g,
                                   (__attribute__((address_space(3))) void*)l, 16, 0, 0);
}

__device__ __forceinline__ bf16x8 cvt8(const float4 a, const float4 b) {
  bf16x8 o;
  o[0]=(bf16_t)a.x; o[1]=(bf16_t)a.y; o[2]=(bf16_t)a.z; o[3]=(bf16_t)a.w;
  o[4]=(bf16_t)b.x; o[5]=(bf16_t)b.y; o[6]=(bf16_t)b.z; o[7]=(bf16_t)b.w;
  return o;
}

// 3-bit bank swizzle: seg position = seg ^ (row&3) ^ ((row>>2)&3). Involution.
__device__ __forceinline__ int segswz(int seg, int row) {
  return seg ^ (row & 3) ^ ((row >> 2) & 3);
}

// ---------------- routing (single block, one launch) ----------------
__global__ void route_all(const int* __restrict__ sel, const float* __restrict__ scal,
                          int* __restrict__ offsets, int* __restrict__ etok,
                          float* __restrict__ escale) {
  __shared__ int cnt[NEXP], cnt2[NEXP], offs[NEXP+1];
  const int t = threadIdx.x;    // 256 threads, 8 entries each
  if (t < NEXP) { cnt[t] = 0; cnt2[t] = 0; }
  __syncthreads();
  int e8[8];
  #pragma unroll
  for (int q = 0; q < 8; q++) {
    int i = t*8 + q;
    e8[q] = sel[i];
    atomicAdd(&cnt[e8[q]], 1);
  }
  __syncthreads();
  if (t == 0) {
    int s = 0;
    for (int e = 0; e < NEXP; e++) { offs[e] = s; offsets[e] = s; s += cnt[e]; }
    offs[NEXP] = s; offsets[NEXP] = s;
  }
  __syncthreads();
  #pragma unroll
  for (int q = 0; q < 8; q++) {
    int i = t*8 + q;
    int e = e8[q];
    int pos = offs[e] + atomicAdd(&cnt2[e], 1);
    etok[pos]   = i >> 1;       // TOPK == 2
    escale[pos] = scal[i];
  }
}

// ---------------- fp32 -> bf16 streaming convert (hidden) ----------------
__global__ void convert_h(const float* __restrict__ h, bf16_t* __restrict__ hbf) {
  size_t idx = ((size_t)blockIdx.x*256 + threadIdx.x) * 8;
  float4 v0 = ((const float4*)(h + idx))[0];
  float4 v1 = ((const float4*)(h + idx))[1];
  *(bf16x8*)(hbf + idx) = cvt8(v0, v1);
}

// ======== v12: REPACKED bf16 weights — GEMM weight fetch is sequential ====
// Six rounds of evidence: GEMM weight fetch stuck at ~1 TB/s (schedule-
// invariant, byte-proportional) while contiguous streamers hit 6.9 TB/s.
// Remaining difference: the GEMM staging reads 64B chunks at 4KB power-of-2
// row stride (DRAM channel/bank aliasing); streamers read contiguously.
// Fix: the convert pass REPACKS weights into per-(expert, n-panel, k-tile)
// 8KB units, pre-swizzled, so each GEMM K-step stages contiguous memory
// (4 x wave-gload16 of sequential 1KB; a block streams a contiguous 256KB
// region over its K-loop). LDS image / frag offsets / MFMA / epilogue are
// byte-identical to v11 — only staging addresses change.
//
// w1r unit u = (e*32 + p)*32 + t   (p: 64-row n-panel, t: 32-wide k-tile)
//   8KB: [gate 4KB | lin 4KB]; within: byte = r*64 + spos*16,
//   content = w1[e][gl][p*64+r][t*32 + s*8 ..], s = segswz(spos, r).
// w2r unit v = (e*8 + q)*64 + tc   (q: 128-row n-panel, tc: k-tile of 64)
//   8KB: byte = r*64 + spos*16, content = w2[e][q*128+r][tc*32 + s*8 ..].

__global__ void repack_w1(const float* __restrict__ w1, bf16_t* __restrict__ w1r) {
  const int u = blockIdx.x;                 // (e*32+p)*32+t, 8192 blocks
  const int t = u & 31, p = (u >> 5) & 31, e = u >> 10;
  const int tid = threadIdx.x;              // 512
  const int gl = tid >> 8, slot = tid & 255;
  const int r = slot >> 2, spos = slot & 3;
  const int s = segswz(spos, r);
  const float* src = w1 + ((size_t)(e*2 + gl)*FDIM + p*64 + r)*HDIM + t*32 + s*8;
  float4 v0 = ((const float4*)src)[0];
  float4 v1 = ((const float4*)src)[1];
  *(bf16x8*)(w1r + (size_t)u*4096 + gl*2048 + slot*8) = cvt8(v0, v1);
}

__global__ void repack_w2(const float* __restrict__ w2, bf16_t* __restrict__ w2r) {
  const int v = blockIdx.x;                 // (e*8+q)*64+tc, 4096 blocks
  const int tc = v & 63, q = (v >> 6) & 7, e = v >> 9;
  const int tid = threadIdx.x;              // 512
  const int r = tid >> 2, spos = tid & 3;
  const int s = segswz(spos, r);
  const float* src = w2 + ((size_t)e*HDIM + q*128 + r)*FDIM + tc*32 + s*8;
  float4 v0 = ((const float4*)src)[0];
  float4 v1 = ((const float4*)src)[1];
  *(bf16x8*)(w2r + (size_t)v*4096 + tid*8) = cvt8(v0, v1);
}

// GEMM1: act = silu(x@w1g^T + b1g) * (x@w1l^T + b1l)   [BM=128, BN=64x2]
__global__ __launch_bounds__(256, 3) void gemm1_v12(
    const bf16_t* __restrict__ hbf, const bf16_t* __restrict__ w1r,
    const float* __restrict__ b1, const int* __restrict__ offsets,
    const int* __restrict__ etok, bf16_t* __restrict__ act)
{
  const int e   = blockIdx.y;
  const int off = offsets[e];
  const int nt  = offsets[e+1] - off;
  const int m0  = blockIdx.z * 128;
  if (m0 >= nt) return;
  const int p   = blockIdx.x;              // n-panel
  const int n0  = p * 64;

  __shared__ __align__(16) bf16_t As[3][128*32];   // 24 KB
  __shared__ __align__(16) bf16_t Bg[3][64*32];    // 12 KB
  __shared__ __align__(16) bf16_t Bl[3][64*32];    // 12 KB

  const int tid  = threadIdx.x;
  const int w    = tid >> 6, lane = tid & 63;
  const int quad = lane >> 4, lr = lane & 15;
  const int wm   = w >> 1,  wn = w & 1;

  // ---- A staging (hbf gather, L2/L3-resident) ----
  const bf16_t* asrc0; const bf16_t* asrc1;
  int arow0, arow1;
  {
    const int r0 = 0*64 + w*16 + (lane >> 2);
    const int r1 = 1*64 + w*16 + (lane >> 2);
    const int s0 = segswz(lane & 3, r0);
    const int s1 = segswz(lane & 3, r1);
    int e0 = m0 + r0; if (e0 > nt-1) e0 = nt-1;   // clamp; masked in epilogue
    int e1 = m0 + r1; if (e1 > nt-1) e1 = nt-1;
    asrc0 = hbf + (size_t)etok[off + e0]*HDIM + s0*8;
    asrc1 = hbf + (size_t)etok[off + e1]*HDIM + s1*8;
    arow0 = (0*64 + w*16)*32;                     // + lane*16B implicit
    arow1 = (1*64 + w*16)*32;
  }

  // ---- B staging: sequential repacked units. Per K-tile T: base + T*4096.
  // K0 is in k-elements (32/tile) -> bf16 offset = K0*128.
  const bf16_t* gW1 = w1r + ((size_t)(e*32 + p)*32)*4096 + w*512 + lane*8;
  const int bofsw = w*512;                  // wave-uniform LDS base (bf16)

  // ---- loop-invariant fragment LDS offsets (identical to v11) ----
  int aoff[4], boff[2];
  #pragma unroll
  for (int i = 0; i < 4; i++) {
    const int r = wm*64 + i*16 + lr;
    aoff[i] = r*32 + (segswz(quad, r) << 3);
  }
  #pragma unroll
  for (int j = 0; j < 2; j++) {
    const int r = wn*32 + j*16 + lr;
    boff[j] = r*32 + (segswz(quad, r) << 3);
  }

  f32x4 accg[4][2] = {}, accl[4][2] = {};

#define G1_STAGE(K0, NXT)                                                     \
  { gload16(asrc0 + (K0), &As[NXT][arow0]);                                   \
    gload16(asrc1 + (K0), &As[NXT][arow1]);                                   \
    gload16(gW1 + (size_t)(K0)*128,        &Bg[NXT][bofsw]);                  \
    gload16(gW1 + (size_t)(K0)*128 + 2048, &Bl[NXT][bofsw]); }

#define G1_MFMA(CUR)                                                          \
  { bf16x8 af[4], gf[2], lf[2];                                               \
    _Pragma("unroll")                                                         \
    for (int i = 0; i < 4; i++) af[i] = *(const bf16x8*)&As[CUR][aoff[i]];    \
    _Pragma("unroll")                                                         \
    for (int j = 0; j < 2; j++) {                                             \
      gf[j] = *(const bf16x8*)&Bg[CUR][boff[j]];                              \
      lf[j] = *(const bf16x8*)&Bl[CUR][boff[j]];                              \
    }                                                                         \
    _Pragma("unroll")                                                         \
    for (int i = 0; i < 4; i++)                                               \
      _Pragma("unroll")                                                       \
      for (int j = 0; j < 2; j++) {                                           \
        accg[i][j] = __builtin_amdgcn_mfma_f32_16x16x32_bf16(af[i], gf[j], accg[i][j], 0, 0, 0); \
        accl[i][j] = __builtin_amdgcn_mfma_f32_16x16x32_bf16(af[i], lf[j], accl[i][j], 0, 0, 0); \
      } }

#define G1_STEP(CUR, NXT)                                                     \
  { G1_STAGE(k0 + 64, NXT);                                                   \
    __builtin_amdgcn_sched_barrier(0);                                        \
    G1_MFMA(CUR);                                                             \
    asm volatile("s_waitcnt vmcnt(4)" ::: "memory");                          \
    __builtin_amdgcn_sched_barrier(0);                                        \
    __builtin_amdgcn_s_barrier();                                             \
    __builtin_amdgcn_sched_barrier(0);                                        \
    k0 += 32; }

  // prologue: stage tiles 0,1; wait tile0 complete (tile1 stays in flight)
  G1_STAGE(0, 0);
  G1_STAGE(32, 1);
  asm volatile("s_waitcnt vmcnt(4)" ::: "memory");
  __builtin_amdgcn_sched_barrier(0);
  __builtin_amdgcn_s_barrier();
  __builtin_amdgcn_sched_barrier(0);

  int k0 = 0;
  while (k0 < 960) {              // t = 0..29, unrolled x3 (10 passes)
    G1_STEP(0, 2);
    G1_STEP(1, 0);
    G1_STEP(2, 1);
  }
  // t = 30 (buf 0): stage(31) still in flight during MFMA, drain after
  G1_MFMA(0);
  asm volatile("s_waitcnt vmcnt(0)" ::: "memory");
  __builtin_amdgcn_sched_barrier(0);
  __builtin_amdgcn_s_barrier();
  __builtin_amdgcn_sched_barrier(0);
  G1_MFMA(1);                     // t = 31 (buf 1)

#undef G1_STEP
#undef G1_MFMA
#undef G1_STAGE

  // epilogue: bias + silu(gate)*lin -> act (bf16)
  #pragma unroll
  for (int j = 0; j < 2; j++) {
    const int f = n0 + wn*32 + j*16 + lr;
    const float bg_ = b1[e*2*FDIM + f];
    const float bl_ = b1[e*2*FDIM + FDIM + f];
    #pragma unroll
    for (int i = 0; i < 4; i++) {
      #pragma unroll
      for (int r = 0; r < 4; r++) {
        const int m = wm*64 + i*16 + quad*4 + r;
        if (m0 + m < nt) {
          const float g = accg[i][j][r] + bg_;
          const float l = accl[i][j][r] + bl_;
          const float s = g / (1.f + __expf(-g)) * l;
          act[(size_t)(off + m0 + m)*FDIM + f] = (bf16_t)s;
        }
      }
    }
  }
}

// GEMM2: y = act @ w2^T + b2; out[token] += scale*y  [BM=128, BN=128, splitK x4]
__global__ __launch_bounds__(256, 3) void gemm2_v12(
    const bf16_t* __restrict__ act, const bf16_t* __restrict__ w2r,
    const float* __restrict__ b2, const int* __restrict__ offsets,
    const int* __restrict__ etok, const float* __restrict__ escale,
    float* __restrict__ out)
{
  const int e   = blockIdx.y;
  const int off = offsets[e];
  const int nt  = offsets[e+1] - off;
  const int m0  = blockIdx.z * 128;
  if (m0 >= nt) return;
  const int q   = blockIdx.x >> 2;         // n-panel (128 rows)
  const int n0  = q * 128;
  const int kc  = blockIdx.x & 3;
  const int kbeg = kc * (FDIM/4);          // 512-chunk, 16 k-tiles

  __shared__ __align__(16) bf16_t As[3][128*32];   // 24 KB
  __shared__ __align__(16) bf16_t Bs[3][128*32];   // 24 KB

  const int tid  = threadIdx.x;
  const int w    = tid >> 6, lane = tid & 63;
  const int quad = lane >> 4, lr = lane & 15;
  const int wm   = w >> 1,  wn = w & 1;

  const bf16_t* asrc0; const bf16_t* asrc1;
  int arow0, arow1;
  {
    const int r0 = 0*64 + w*16 + (lane >> 2);
    const int r1 = 1*64 + w*16 + (lane >> 2);
    const int s0 = segswz(lane & 3, r0);
    const int s1 = segswz(lane & 3, r1);
    int e0 = m0 + r0; if (e0 > nt-1) e0 = nt-1;
    int e1 = m0 + r1; if (e1 > nt-1) e1 = nt-1;
    asrc0 = act + (size_t)(off + e0)*FDIM + kbeg + s0*8;
    asrc1 = act + (size_t)(off + e1)*FDIM + kbeg + s1*8;
    arow0 = (0*64 + w*16)*32;
    arow1 = (1*64 + w*16)*32;
  }

  // B staging: sequential repacked units, base at this chunk's first k-tile.
  const bf16_t* bW2 = w2r + ((size_t)((e*8 + q)*64 + kc*16))*4096 + w*1024 + lane*8;
  const int bofsw = w*1024;                // wave-uniform LDS base (bf16)

  int aoff[4], boff[4];
  #pragma unroll
  for (int i = 0; i < 4; i++) {
    const int r = wm*64 + i*16 + lr;
    aoff[i] = r*32 + (segswz(quad, r) << 3);
  }
  #pragma unroll
  for (int j = 0; j < 4; j++) {
    const int r = wn*64 + j*16 + lr;
    boff[j] = r*32 + (segswz(quad, r) << 3);
  }

  f32x4 acc[4][4] = {};

#define G2_STAGE(K0, NXT)                                                     \
  { gload16(asrc0 + (K0), &As[NXT][arow0]);                                   \
    gload16(asrc1 + (K0), &As[NXT][arow1]);                                   \
    gload16(bW2 + (size_t)(K0)*128,       &Bs[NXT][bofsw]);                   \
    gload16(bW2 + (size_t)(K0)*128 + 512, &Bs[NXT][bofsw + 512]); }

#define G2_MFMA(CUR)                                                          \
  { bf16x8 af[4], bfr[4];                                                     \
    _Pragma("unroll")                                                         \
    for (int i = 0; i < 4; i++) af[i] = *(const bf16x8*)&As[CUR][aoff[i]];    \
    _Pragma("unroll")                                                         \
    for (int j = 0; j < 4; j++) bfr[j] = *(const bf16x8*)&Bs[CUR][boff[j]];   \
    _Pragma("unroll")                                                         \
    for (int i = 0; i < 4; i++)                                               \
      _Pragma("unroll")                                                       \
      for (int j = 0; j < 4; j++)                                             \
        acc[i][j] = __builtin_amdgcn_mfma_f32_16x16x32_bf16(af[i], bfr[j], acc[i][j], 0, 0, 0); }

#define G2_STEP(CUR, NXT)                                                     \
  { G2_STAGE(k0 + 64, NXT);                                                   \
    __builtin_amdgcn_sched_barrier(0);                                        \
    G2_MFMA(CUR);                                                             \
    asm volatile("s_waitcnt vmcnt(4)" ::: "memory");                          \
    __builtin_amdgcn_sched_barrier(0);                                        \
    __builtin_amdgcn_s_barrier();                                             \
    __builtin_amdgcn_sched_barrier(0);                                        \
    k0 += 32; }

  // prologue: stage tiles 0,1
  G2_STAGE(0, 0);
  G2_STAGE(32, 1);
  asm volatile("s_waitcnt vmcnt(4)" ::: "memory");
  __builtin_amdgcn_sched_barrier(0);
  __builtin_amdgcn_s_barrier();
  __builtin_amdgcn_sched_barrier(0);

  int k0 = 0;
  while (k0 < 384) {              // t = 0..11, unrolled x3 (4 passes)
    G2_STEP(0, 2);
    G2_STEP(1, 0);
    G2_STEP(2, 1);
  }
  G2_STEP(0, 2);                  // t = 12: stages tile14 -> buf2
  G2_STEP(1, 0);                  // t = 13: stages tile15 -> buf0
  // t = 14 (buf 2): tile15's stage in flight during MFMA, drain after
  G2_MFMA(2);
  asm volatile("s_waitcnt vmcnt(0)" ::: "memory");
  __builtin_amdgcn_sched_barrier(0);
  __builtin_amdgcn_s_barrier();
  __builtin_amdgcn_sched_barrier(0);
  G2_MFMA(0);                     // t = 15 (buf 0)

#undef G2_STEP
#undef G2_MFMA
#undef G2_STAGE

  // epilogue: + b2 (k-chunk 0 only), scale, atomic scatter-add
  #pragma unroll
  for (int i = 0; i < 4; i++) {
    #pragma unroll
    for (int r = 0; r < 4; r++) {
      const int m = wm*64 + i*16 + quad*4 + r;
      if (m0 + m < nt) {
        const int slot = off + m0 + m;
        const int t    = etok[slot];
        const float s  = escale[slot];
        #pragma unroll
        for (int j = 0; j < 4; j++) {
          const int n = n0 + wn*64 + j*16 + lr;
          float v = acc[i][j][r];
          if (kc == 0) v += b2[e*HDIM + n];
          atomicAdd(&out[(size_t)t*HDIM + n], s * v);
        }
      }
    }
  }
}

// ======== fallback (round-3 fp32-weight kernels, used if ws too small) ====
__global__ __launch_bounds__(256, 3) void gemm1_v8(
    const bf16_t* __restrict__ hbf, const float* __restrict__ w1,
    const float* __restrict__ b1, const int* __restrict__ offsets,
    const int* __restrict__ etok, bf16_t* __restrict__ act)
{
  const int e   = blockIdx.y;
  const int off = offsets[e];
  const int nt  = offsets[e+1] - off;
  const int m0  = blockIdx.z * 128;
  if (m0 >= nt) return;
  const int n0  = blockIdx.x * 64;

  __shared__ __align__(16) bf16_t As[2][128*32];
  __shared__ __align__(16) bf16_t Bg[2][64*32];
  __shared__ __align__(16) bf16_t Bl[2][64*32];

  const int tid  = threadIdx.x;
  const int w    = tid >> 6, lane = tid & 63;
  const int quad = lane >> 4, lr = lane & 15;
  const int wm   = w >> 1,  wn = w & 1;

  const bf16_t* asrc0; const bf16_t* asrc1;
  int arow0, arow1;
  {
    const int r0 = 0*64 + w*16 + (lane >> 2);
    const int r1 = 1*64 + w*16 + (lane >> 2);
    const int s0 = segswz(lane & 3, r0);
    const int s1 = segswz(lane & 3, r1);
    int e0 = m0 + r0; if (e0 > nt-1) e0 = nt-1;
    int e1 = m0 + r1; if (e1 > nt-1) e1 = nt-1;
    asrc0 = hbf + (size_t)etok[off + e0]*HDIM + s0*8;
    asrc1 = hbf + (size_t)etok[off + e1]*HDIM + s1*8;
    arow0 = (0*64 + w*16)*32;
    arow1 = (1*64 + w*16)*32;
  }

  const int br = tid >> 2, bs = tid & 3;
  const float* gsrc = w1 + ((size_t)e*2*FDIM + (size_t)(n0 + br))*HDIM + bs*8;
  const float* lsrc = gsrc + (size_t)FDIM*HDIM;
  const int bofs = br*32 + (segswz(bs, br) << 3);

  int aoff[4], boff[2];
  #pragma unroll
  for (int i = 0; i < 4; i++) {
    const int r = wm*64 + i*16 + lr;
    aoff[i] = r*32 + (segswz(quad, r) << 3);
  }
  #pragma unroll
  for (int j = 0; j < 2; j++) {
    const int r = wn*32 + j*16 + lr;
    boff[j] = r*32 + (segswz(quad, r) << 3);
  }

  f32x4 accg[4][2] = {}, accl[4][2] = {};
  float4 g4[2][2], l4[2][2];

#define F1_LOADB(SET, K0)                                                     \
  { const float4* p_ = (const float4*)(gsrc + (K0));                          \
    g4[SET][0]=p_[0]; g4[SET][1]=p_[1];                                       \
    const float4* q_ = (const float4*)(lsrc + (K0));                          \
    l4[SET][0]=q_[0]; l4[SET][1]=q_[1]; }
#define F1_WRITEB(NXT, SET)                                                   \
  { *(bf16x8*)&Bg[NXT][bofs] = cvt8(g4[SET][0], g4[SET][1]);                  \
    *(bf16x8*)&Bl[NXT][bofs] = cvt8(l4[SET][0], l4[SET][1]); }
#define F1_MFMA(CUR)                                                          \
  { bf16x8 af[4], gf[2], lf[2];                                               \
    _Pragma("unroll")                                                         \
    for (int i = 0; i < 4; i++) af[i] = *(const bf16x8*)&As[CUR][aoff[i]];    \
    _Pragma("unroll")                                                         \
    for (int j = 0; j < 2; j++) {                                             \
      gf[j] = *(const bf16x8*)&Bg[CUR][boff[j]];                              \
      lf[j] = *(const bf16x8*)&Bl[CUR][boff[j]];                              \
    }                                                                         \
    _Pragma("unroll")                                                         \
    for (int i = 0; i < 4; i++)                                               \
      _Pragma("unroll")                                                       \
      for (int j = 0; j < 2; j++) {                                           \
        accg[i][j] = __builtin_amdgcn_mfma_f32_16x16x32_bf16(af[i], gf[j], accg[i][j], 0, 0, 0); \
        accl[i][j] = __builtin_amdgcn_mfma_f32_16x16x32_bf16(af[i], lf[j], accl[i][j], 0, 0, 0); \
      } }

  F1_LOADB(0, 0);
  __builtin_amdgcn_sched_barrier(0);
  gload16(asrc0 + 0, &As[0][arow0]);
  gload16(asrc1 + 0, &As[0][arow1]);
  __builtin_amdgcn_sched_barrier(0);
  F1_WRITEB(0, 0);
  F1_LOADB(0, 32);
  F1_LOADB(1, 64);
  asm volatile("s_waitcnt vmcnt(8) lgkmcnt(0)" ::: "memory");
  __builtin_amdgcn_sched_barrier(0);
  __builtin_amdgcn_s_barrier();
  __builtin_amdgcn_sched_barrier(0);

#define F1_STEP(CUR, SET)                                                     \
  { F1_WRITEB((CUR)^1, SET);                                                  \
    __builtin_amdgcn_sched_barrier(0);                                        \
    gload16(asrc0 + k0 + 32, &As[(CUR)^1][arow0]);                            \
    gload16(asrc1 + k0 + 32, &As[(CUR)^1][arow1]);                            \
    __builtin_amdgcn_sched_barrier(0);                                        \
    F1_LOADB(SET, k0 + 96);                                                   \
    __builtin_amdgcn_sched_barrier(0);                                        \
    F1_MFMA(CUR);                                                             \
    asm volatile("s_waitcnt vmcnt(4) lgkmcnt(0)" ::: "memory");               \
    __builtin_amdgcn_sched_barrier(0);                                        \
    __builtin_amdgcn_s_barrier();                                             \
    __builtin_amdgcn_sched_barrier(0);                                        \
    k0 += 32; }

  int k0 = 0;
  while (k0 < 896) { F1_STEP(0, 0); F1_STEP(1, 1); }
  F1_STEP(0, 0);
  F1_WRITEB(0, 1);
  __builtin_amdgcn_sched_barrier(0);
  gload16(asrc0 + 960, &As[0][arow0]);
  gload16(asrc1 + 960, &As[0][arow1]);
  __builtin_amdgcn_sched_barrier(0);
  F1_MFMA(1);
  asm volatile("s_waitcnt vmcnt(0) lgkmcnt(0)" ::: "memory");
  __builtin_amdgcn_sched_barrier(0);
  __builtin_amdgcn_s_barrier();
  __builtin_amdgcn_sched_barrier(0);
  F1_WRITEB(1, 0);
  __builtin_amdgcn_sched_barrier(0);
  gload16(asrc0 + 992, &As[1][arow0]);
  gload16(asrc1 + 992, &As[1][arow1]);
  __builtin_amdgcn_sched_barrier(0);
  F1_MFMA(0);
  asm volatile("s_waitcnt vmcnt(0) lgkmcnt(0)" ::: "memory");
  __builtin_amdgcn_sched_barrier(0);
  __builtin_amdgcn_s_barrier();
  __builtin_amdgcn_sched_barrier(0);
  F1_MFMA(1);

#undef F1_STEP
#undef F1_MFMA
#undef F1_WRITEB
#undef F1_LOADB

  #pragma unroll
  for (int j = 0; j < 2; j++) {
    const int f = n0 + wn*32 + j*16 + lr;
    const float bg_ = b1[e*2*FDIM + f];
    const float bl_ = b1[e*2*FDIM + FDIM + f];
    #pragma unroll
    for (int i = 0; i < 4; i++) {
      #pragma unroll
      for (int r = 0; r < 4; r++) {
        const int m = wm*64 + i*16 + quad*4 + r;
        if (m0 + m < nt) {
          const float g = accg[i][j][r] + bg_;
          const float l = accl[i][j][r] + bl_;
          const float s = g / (1.f + __expf(-g)) * l;
          act[(size_t)(off + m0 + m)*FDIM + f] = (bf16_t)s;
        }
      }
    }
  }
}

__global__ __launch_bounds__(256, 3) void gemm2_v8(
    const bf16_t* __restrict__ act, const float* __restrict__ w2,
    const float* __restrict__ b2, const int* __restrict__ offsets,
    const int* __restrict__ etok, const float* __restrict__ escale,
    float* __restrict__ out)
{
  const int e   = blockIdx.y;
  const int off = offsets[e];
  const int nt  = offsets[e+1] - off;
  const int m0  = blockIdx.z * 128;
  if (m0 >= nt) return;
  const int n0  = (blockIdx.x >> 2) * 128;
  const int kc  = blockIdx.x & 3;
  const int kbeg = kc * (FDIM/4);

  __shared__ __align__(16) bf16_t As[2][128*32];
  __shared__ __align__(16) bf16_t Bs[2][128*32];

  const int tid  = threadIdx.x;
  const int w    = tid >> 6, lane = tid & 63;
  const int quad = lane >> 4, lr = lane & 15;
  const int wm   = w >> 1,  wn = w & 1;

  const bf16_t* asrc0; const bf16_t* asrc1;
  int arow0, arow1;
  {
    const int r0 = 0*64 + w*16 + (lane >> 2);
    const int r1 = 1*64 + w*16 + (lane >> 2);
    const int s0 = segswz(lane & 3, r0);
    const int s1 = segswz(lane & 3, r1);
    int e0 = m0 + r0; if (e0 > nt-1) e0 = nt-1;
    int e1 = m0 + r1; if (e1 > nt-1) e1 = nt-1;
    asrc0 = act + (size_t)(off + e0)*FDIM + kbeg + s0*8;
    asrc1 = act + (size_t)(off + e1)*FDIM + kbeg + s1*8;
    arow0 = (0*64 + w*16)*32;
    arow1 = (1*64 + w*16)*32;
  }

  const int br = tid >> 1, bc = tid & 1;
  const float* bsrc = w2 + ((size_t)e*HDIM + (size_t)(n0 + br))*FDIM + kbeg + bc*16;
  const int bofs0 = br*32 + (segswz(2*bc,   br) << 3);
  const int bofs1 = br*32 + (segswz(2*bc+1, br) << 3);

  int aoff[4], boff[4];
  #pragma unroll
  for (int i = 0; i < 4; i++) {
    const int r = wm*64 + i*16 + lr;
    aoff[i] = r*32 + (segswz(quad, r) << 3);
  }
  #pragma unroll
  for (int j = 0; j < 4; j++) {
    const int r = wn*64 + j*16 + lr;
    boff[j] = r*32 + (segswz(quad, r) << 3);
  }

  f32x4 acc[4][4] = {};
  float4 b4[2][4];

#define F2_LOADB(SET, K0)                                                     \
  { const float4* p_ = (const float4*)(bsrc + (K0));                          \
    b4[SET][0]=p_[0]; b4[SET][1]=p_[1]; b4[SET][2]=p_[2]; b4[SET][3]=p_[3]; }
#define F2_WRITEB(NXT, SET)                                                   \
  { *(bf16x8*)&Bs[NXT][bofs0] = cvt8(b4[SET][0], b4[SET][1]);                 \
    *(bf16x8*)&Bs[NXT][bofs1] = cvt8(b4[SET][2], b4[SET][3]); }
#define F2_MFMA(CUR)                                                          \
  { bf16x8 af[4], bfr[4];                                                     \
    _Pragma("unroll")                                                         \
    for (int i = 0; i < 4; i++) af[i] = *(const bf16x8*)&As[CUR][aoff[i]];    \
    _Pragma("unroll")                                                         \
    for (int j = 0; j < 4; j++) bfr[j] = *(const bf16x8*)&Bs[CUR][boff[j]];   \
    _Pragma("unroll")                                                         \
    for (int i = 0; i < 4; i++)                                               \
      _Pragma("unroll")                                                       \
      for (int j = 0; j < 4; j++)                                             \
        acc[i][j] = __builtin_amdgcn_mfma_f32_16x16x32_bf16(af[i], bfr[j], acc[i][j], 0, 0, 0); }

  F2_LOADB(0, 0);
  __builtin_amdgcn_sched_barrier(0);
  gload16(asrc0 + 0, &As[0][arow0]);
  gload16(asrc1 + 0, &As[0][arow1]);
  __builtin_amdgcn_sched_barrier(0);
  F2_WRITEB(0, 0);
  F2_LOADB(0, 32);
  F2_LOADB(1, 64);
  asm volatile("s_waitcnt vmcnt(8) lgkmcnt(0)" ::: "memory");
  __builtin_amdgcn_sched_barrier(0);
  __builtin_amdgcn_s_barrier();
  __builtin_amdgcn_sched_barrier(0);

#define F2_STEP(CUR, SET)                                                     \
  { F2_WRITEB((CUR)^1, SET);                                                  \
    __builtin_amdgcn_sched_barrier(0);                                        \
    gload16(asrc0 + k0 + 32, &As[(CUR)^1][arow0]);                            \
    gload16(asrc1 + k0 + 32, &As[(CUR)^1][arow1]);                            \
    __builtin_amdgcn_sched_barrier(0);                                        \
    F2_LOADB(SET, k0 + 96);                                                   \
    __builtin_amdgcn_sched_barrier(0);                                        \
    F2_MFMA(CUR);                                                             \
    asm volatile("s_waitcnt vmcnt(4) lgkmcnt(0)" ::: "memory");               \
    __builtin_amdgcn_sched_barrier(0);                                        \
    __builtin_amdgcn_s_barrier();                                             \
    __builtin_amdgcn_sched_barrier(0);                                        \
    k0 += 32; }

  int k0 = 0;
  while (k0 < 384) { F2_STEP(0, 0); F2_STEP(1, 1); }
  F2_STEP(0, 0);
  F2_WRITEB(0, 1);
  __builtin_amdgcn_sched_barrier(0);
  gload16(asrc0 + 448, &As[0][arow0]);
  gload16(asrc1 + 448, &As[0][arow1]);
  __builtin_amdgcn_sched_barrier(0);
  F2_MFMA(1);
  asm volatile("s_waitcnt vmcnt(0) lgkmcnt(0)" ::: "memory");
  __builtin_amdgcn_sched_barrier(0);
  __builtin_amdgcn_s_barrier();
  __builtin_amdgcn_sched_barrier(0);
  F2_WRITEB(1, 0);
  __builtin_amdgcn_sched_barrier(0);
  gload16(asrc0 + 480, &As[1][arow0]);
  gload16(asrc1 + 480, &As[1][arow1]);
  __builtin_amdgcn_sched_barrier(0);
  F2_MFMA(0);
  asm volatile("s_waitcnt vmcnt(0) lgkmcnt(0)" ::: "memory");
  __builtin_amdgcn_sched_barrier(0);
  __builtin_amdgcn_s_barrier();
  __builtin_amdgcn_sched_barrier(0);
  F2_MFMA(1);

#undef F2_STEP
#undef F2_MFMA
#undef F2_WRITEB
#undef F2_LOADB

  #pragma unroll
  for (int i = 0; i < 4; i++) {
    #pragma unroll
    for (int r = 0; r < 4; r++) {
      const int m = wm*64 + i*16 + quad*4 + r;
      if (m0 + m < nt) {
        const int slot = off + m0 + m;
        const int t    = etok[slot];
        const float s  = escale[slot];
        #pragma unroll
        for (int j = 0; j < 4; j++) {
          const int n = n0 + wn*64 + j*16 + lr;
          float v = acc[i][j][r];
          if (kc == 0) v += b2[e*HDIM + n];
          atomicAdd(&out[(size_t)t*HDIM + n], s * v);
        }
      }
    }
  }
}

extern "C" void kernel_launch(void* const* d_in, const int* in_sizes, int n_in,
                              void* d_out, int out_size, void* d_ws, size_t ws_size,
                              hipStream_t stream) {
  const float* hidden = (const float*)d_in[0];
  const int*   sel    = (const int*)d_in[1];
  const float* scal   = (const float*)d_in[2];
  const float* w1     = (const float*)d_in[3];
  const float* b1     = (const float*)d_in[4];
  const float* w2     = (const float*)d_in[5];
  const float* b2     = (const float*)d_in[6];
  float* out = (float*)d_out;

  char* ws = (char*)d_ws;
  int*    offsets = (int*)(ws + WB_OFFSETS);
  int*    etok    = (int*)(ws + WB_ETOK);
  float*  escale  = (float*)(ws + WB_ESCALE);
  bf16_t* act     = (bf16_t*)(ws + WB_ACT);
  bf16_t* hbf     = (bf16_t*)(ws + WB_H);
  bf16_t* w2r     = (bf16_t*)(ws + WB_W2BF);
  bf16_t* w1r     = (bf16_t*)(ws + WB_W1BF);

  hipMemsetAsync(d_out, 0, (size_t)out_size * sizeof(float), stream);

  route_all<<<1, 256, 0, stream>>>(sel, scal, offsets, etok, escale);
  convert_h<<<(int)(H_ELEMS/8/256), 256, 0, stream>>>(hidden, hbf);

  if (ws_size >= WB_NEED) {
    // repack weights into GEMM-native sequential tile units (w2 first so
    // w1r is freshest in L3 when gemm1 runs), then sequential-fetch GEMMs.
    repack_w2<<<NEXP*8*64, 512, 0, stream>>>(w2, w2r);
    repack_w1<<<NEXP*32*32, 512, 0, stream>>>(w1, w1r);
    gemm1_v12<<<dim3(FDIM/64, NEXP, NENT/128), 256, 0, stream>>>(hbf, w1r, b1, offsets, etok, act);
    gemm2_v12<<<dim3((HDIM/128)*4, NEXP, NENT/128), 256, 0, stream>>>(act, w2r, b2, offsets, etok, escale, out);
  } else {
    // fallback: round-3 fp32-weight kernels
    gemm1_v8<<<dim3(FDIM/64, NEXP, NENT/128), 256, 0, stream>>>(hbf, w1, b1, offsets, etok, act);
    gemm2_v8<<<dim3((HDIM/128)*4, NEXP, NENT/128), 256, 0, stream>>>(act, w2, b2, offsets, etok, escale, out);
  }
}

// Round 8
// 339.700 us; speedup vs baseline: 1.0749x; 1.0749x over previous
//
#include <hip/hip_runtime.h>
#include <hip/hip_bf16.h>
#include <cstdint>
#include <cstddef>

// Problem constants (fixed by the reference)
#define TDIM 1024
#define HDIM 1024
#define FDIM 2048
#define NEXP 8
#define NENT 2048   // T * K

typedef __bf16 bf16_t;
typedef __bf16 bf16x4 __attribute__((ext_vector_type(4)));
typedef __bf16 bf16x8 __attribute__((ext_vector_type(8)));
typedef float  f32x4  __attribute__((ext_vector_type(4)));

#define H_ELEMS ((size_t)TDIM*HDIM)   // 1048576

// ---------------- workspace layout (bytes) ----------------
#define WB_OFFSETS 0                                   // int[16]
#define WB_ETOK    64
#define WB_ESCALE  (WB_ETOK + NENT*4)
#define WB_ACT     16512                               // bf16[NENT][FDIM] = 8 MB
#define WB_H       (WB_ACT + (size_t)NENT*FDIM*2)      // bf16[T][H] = 2 MB

__device__ __forceinline__ void gload16(const void* g, void* l) {
  __builtin_amdgcn_global_load_lds((const __attribute__((address_space(1))) void*)g,
                                   (__attribute__((address_space(3))) void*)l, 16, 0, 0);
}

__device__ __forceinline__ bf16x8 cvt8(const float4 a, const float4 b) {
  bf16x8 o;
  o[0]=(bf16_t)a.x; o[1]=(bf16_t)a.y; o[2]=(bf16_t)a.z; o[3]=(bf16_t)a.w;
  o[4]=(bf16_t)b.x; o[5]=(bf16_t)b.y; o[6]=(bf16_t)b.z; o[7]=(bf16_t)b.w;
  return o;
}

// 3-bit bank swizzle: seg position = seg ^ (row&3) ^ ((row>>2)&3). Involution.
__device__ __forceinline__ int segswz(int seg, int row) {
  return seg ^ (row & 3) ^ ((row >> 2) & 3);
}

// ---------------- routing (single block, one launch) ----------------
__global__ void route_all(const int* __restrict__ sel, const float* __restrict__ scal,
                          int* __restrict__ offsets, int* __restrict__ etok,
                          float* __restrict__ escale) {
  __shared__ int cnt[NEXP], cnt2[NEXP], offs[NEXP+1];
  const int t = threadIdx.x;    // 256 threads, 8 entries each
  if (t < NEXP) { cnt[t] = 0; cnt2[t] = 0; }
  __syncthreads();
  int e8[8];
  #pragma unroll
  for (int q = 0; q < 8; q++) {
    int i = t*8 + q;
    e8[q] = sel[i];
    atomicAdd(&cnt[e8[q]], 1);
  }
  __syncthreads();
  if (t == 0) {
    int s = 0;
    for (int e = 0; e < NEXP; e++) { offs[e] = s; offsets[e] = s; s += cnt[e]; }
    offs[NEXP] = s; offsets[NEXP] = s;
  }
  __syncthreads();
  #pragma unroll
  for (int q = 0; q < 8; q++) {
    int i = t*8 + q;
    int e = e8[q];
    int pos = offs[e] + atomicAdd(&cnt2[e], 1);
    etok[pos]   = i >> 1;       // TOPK == 2
    escale[pos] = scal[i];
  }
}

// ---------------- hidden fp32 -> bf16 ----------------
__global__ void convert_h(const float* __restrict__ h, bf16_t* __restrict__ hbf) {
  size_t idx = ((size_t)blockIdx.x*256 + threadIdx.x) * 8;
  float4 v0 = ((const float4*)(h + idx))[0];
  float4 v1 = ((const float4*)(h + idx))[1];
  *(bf16x8*)(hbf + idx) = cvt8(v0, v1);
}

// ======== v13: v8 structure (best: 328.5) + DOUBLED LIVE BLOCKS ========
// Eight rounds of evidence: every config had ~512 live blocks = 2/CU =
// 8 waves/CU (measured occupancy 22-27%), and the grid — not LDS/VGPR —
// was the cap. Barrier-synced pairs of blocks can't keep the fetch path
// busy (repack kernels with 4096 free-running blocks fetch the same bytes
// with the same stride pattern >2x faster). v13 halves BN in both GEMMs:
// 1024 live blocks = 4/CU = 16 waves/CU. B-side HBM demand is unchanged
// (it scales with m-tiles); the extra A-side demand is L2/L3-resident.
// fp32 weights read directly (bf16-convert & repack passes were net losses).

// GEMM1: act = silu(x@w1g^T + b1g) * (x@w1l^T + b1l)   [BM=128, BN=32]
__global__ __launch_bounds__(256, 4) void gemm1_v13(
    const bf16_t* __restrict__ hbf, const float* __restrict__ w1,
    const float* __restrict__ b1, const int* __restrict__ offsets,
    const int* __restrict__ etok, bf16_t* __restrict__ act)
{
  const int e   = blockIdx.y;
  const int off = offsets[e];
  const int nt  = offsets[e+1] - off;
  const int m0  = blockIdx.z * 128;
  if (m0 >= nt) return;
  const int n0  = blockIdx.x * 32;

  __shared__ __align__(16) bf16_t As[2][128*32];   // 16 KB
  __shared__ __align__(16) bf16_t Bg[2][32*32];    //  4 KB
  __shared__ __align__(16) bf16_t Bl[2][32*32];    //  4 KB

  const int tid  = threadIdx.x;
  const int w    = tid >> 6, lane = tid & 63;
  const int quad = lane >> 4, lr = lane & 15;
  const int wm   = w >> 1,  wn = w & 1;            // 2m x 2n (64m x 16n)

  // ---- A staging: wave w, inst i covers LDS rows [i*64 + w*16, +16) ----
  const bf16_t* asrc0; const bf16_t* asrc1;
  int arow0, arow1;
  {
    const int r0 = 0*64 + w*16 + (lane >> 2);
    const int r1 = 1*64 + w*16 + (lane >> 2);
    const int s0 = segswz(lane & 3, r0);
    const int s1 = segswz(lane & 3, r1);
    int e0 = m0 + r0; if (e0 > nt-1) e0 = nt-1;   // clamp; masked in epilogue
    int e1 = m0 + r1; if (e1 > nt-1) e1 = nt-1;
    asrc0 = hbf + (size_t)etok[off + e0]*HDIM + s0*8;
    asrc1 = hbf + (size_t)etok[off + e1]*HDIM + s1*8;
    arow0 = (0*64 + w*16)*32;                     // + lane*16B implicit
    arow1 = (1*64 + w*16)*32;
  }

  // ---- B staging: tid<128 -> gate, tid>=128 -> lin; slot: row(32) x seg(4)
  const int gl = tid >> 7, slot = tid & 127;
  const int br = slot >> 2, bs = slot & 3;
  const float* bsrc = w1 + ((size_t)(e*2 + gl)*FDIM + (size_t)(n0 + br))*HDIM + bs*8;
  const int bofs = br*32 + (segswz(bs, br) << 3);
  bf16_t* const bq = gl ? &Bl[0][0] : &Bg[0][0];   // + NXT*1024 + bofs

  // ---- loop-invariant fragment LDS offsets ----
  int aoff[4], boff;
  #pragma unroll
  for (int i = 0; i < 4; i++) {
    const int r = wm*64 + i*16 + lr;
    aoff[i] = r*32 + (segswz(quad, r) << 3);
  }
  { const int r = wn*16 + lr;
    boff = r*32 + (segswz(quad, r) << 3); }

  f32x4 accg[4] = {}, accl[4] = {};
  float4 b4[2][2];               // depth-2 ping-pong B regs (2 float4 each)

#define G1_LOADB(SET, K0)                                                     \
  { const float4* p_ = (const float4*)(bsrc + (K0));                          \
    b4[SET][0]=p_[0]; b4[SET][1]=p_[1]; }

#define G1_WRITEB(NXT, SET)                                                   \
  { *(bf16x8*)(bq + (NXT)*1024 + bofs) = cvt8(b4[SET][0], b4[SET][1]); }

#define G1_MFMA(CUR)                                                          \
  { bf16x8 af[4], gf, lf;                                                     \
    _Pragma("unroll")                                                         \
    for (int i = 0; i < 4; i++) af[i] = *(const bf16x8*)&As[CUR][aoff[i]];    \
    gf = *(const bf16x8*)&Bg[CUR][boff];                                      \
    lf = *(const bf16x8*)&Bl[CUR][boff];                                      \
    _Pragma("unroll")                                                         \
    for (int i = 0; i < 4; i++) {                                             \
      accg[i] = __builtin_amdgcn_mfma_f32_16x16x32_bf16(af[i], gf, accg[i], 0, 0, 0); \
      accl[i] = __builtin_amdgcn_mfma_f32_16x16x32_bf16(af[i], lf, accl[i], 0, 0, 0); \
    } }

  // ---- prologue: tile0 -> buf0; B(1)->set0, B(2)->set1 in flight ----
  G1_LOADB(0, 0);                                // B(0) -> set0, 2 vm
  __builtin_amdgcn_sched_barrier(0);
  gload16(asrc0 + 0, &As[0][arow0]);             // A(0), 2 vm
  gload16(asrc1 + 0, &As[0][arow1]);
  __builtin_amdgcn_sched_barrier(0);
  G1_WRITEB(0, 0);                               // compiler drains B(0) regs
  G1_LOADB(0, 32);                               // B(1) -> set0, 2 vm
  G1_LOADB(1, 64);                               // B(2) -> set1, 2 vm
  asm volatile("s_waitcnt vmcnt(4) lgkmcnt(0)" ::: "memory");  // A(0) done
  __builtin_amdgcn_sched_barrier(0);
  __builtin_amdgcn_s_barrier();
  __builtin_amdgcn_sched_barrier(0);

  // steady step at tile t: write B(t+1) from SET (loaded t-2), stage A(t+1),
  // issue B(t+3) -> SET, compute tile t. vmcnt(2): drains A(t+1)+B(t+2),
  // leaves B(t+3)'s 2 loads in flight across the barrier.
#define G1_STEP(CUR, SET)                                                     \
  { G1_WRITEB((CUR)^1, SET);                                                  \
    __builtin_amdgcn_sched_barrier(0);                                        \
    gload16(asrc0 + k0 + 32, &As[(CUR)^1][arow0]);                            \
    gload16(asrc1 + k0 + 32, &As[(CUR)^1][arow1]);                            \
    __builtin_amdgcn_sched_barrier(0);                                        \
    G1_LOADB(SET, k0 + 96);                                                   \
    __builtin_amdgcn_sched_barrier(0);                                        \
    G1_MFMA(CUR);                                                             \
    asm volatile("s_waitcnt vmcnt(2) lgkmcnt(0)" ::: "memory");               \
    __builtin_amdgcn_sched_barrier(0);                                        \
    __builtin_amdgcn_s_barrier();                                             \
    __builtin_amdgcn_sched_barrier(0);                                        \
    k0 += 32; }

  int k0 = 0;
  while (k0 < 896) {              // t = 0..27 (pairs)
    G1_STEP(0, 0);
    G1_STEP(1, 1);
  }
  G1_STEP(0, 0);                  // t = 28: loads B(31) at k0+96 = 992
  // t = 29 (CUR = 1): write B(30) from set1, stage A(30), no B-load
  G1_WRITEB(0, 1);
  __builtin_amdgcn_sched_barrier(0);
  gload16(asrc0 + 960, &As[0][arow0]);
  gload16(asrc1 + 960, &As[0][arow1]);
  __builtin_amdgcn_sched_barrier(0);
  G1_MFMA(1);
  asm volatile("s_waitcnt vmcnt(0) lgkmcnt(0)" ::: "memory");
  __builtin_amdgcn_sched_barrier(0);
  __builtin_amdgcn_s_barrier();
  __builtin_amdgcn_sched_barrier(0);
  // t = 30 (CUR = 0): write B(31) from set0, stage A(31)
  G1_WRITEB(1, 0);
  __builtin_amdgcn_sched_barrier(0);
  gload16(asrc0 + 992, &As[1][arow0]);
  gload16(asrc1 + 992, &As[1][arow1]);
  __builtin_amdgcn_sched_barrier(0);
  G1_MFMA(0);
  asm volatile("s_waitcnt vmcnt(0) lgkmcnt(0)" ::: "memory");
  __builtin_amdgcn_sched_barrier(0);
  __builtin_amdgcn_s_barrier();
  __builtin_amdgcn_sched_barrier(0);
  // t = 31
  G1_MFMA(1);

#undef G1_STEP
#undef G1_MFMA
#undef G1_WRITEB
#undef G1_LOADB

  // epilogue: bias + silu(gate)*lin -> act (bf16)
  {
    const int f = n0 + wn*16 + lr;
    const float bg_ = b1[e*2*FDIM + f];
    const float bl_ = b1[e*2*FDIM + FDIM + f];
    #pragma unroll
    for (int i = 0; i < 4; i++) {
      #pragma unroll
      for (int r = 0; r < 4; r++) {
        const int m = wm*64 + i*16 + quad*4 + r;
        if (m0 + m < nt) {
          const float g = accg[i][r] + bg_;
          const float l = accl[i][r] + bl_;
          const float s = g / (1.f + __expf(-g)) * l;
          act[(size_t)(off + m0 + m)*FDIM + f] = (bf16_t)s;
        }
      }
    }
  }
}

// GEMM2: y = act @ w2^T + b2; out[token] += scale*y  [BM=128, BN=64, splitK x4]
__global__ __launch_bounds__(256, 4) void gemm2_v13(
    const bf16_t* __restrict__ act, const float* __restrict__ w2,
    const float* __restrict__ b2, const int* __restrict__ offsets,
    const int* __restrict__ etok, const float* __restrict__ escale,
    float* __restrict__ out)
{
  const int e   = blockIdx.y;
  const int off = offsets[e];
  const int nt  = offsets[e+1] - off;
  const int m0  = blockIdx.z * 128;
  if (m0 >= nt) return;
  const int n0  = (blockIdx.x >> 2) * 64;
  const int kc  = blockIdx.x & 3;
  const int kbeg = kc * (FDIM/4);          // 512-chunk, 16 iters

  __shared__ __align__(16) bf16_t As[2][128*32];   // 16 KB
  __shared__ __align__(16) bf16_t Bs[2][64*32];    //  8 KB

  const int tid  = threadIdx.x;
  const int w    = tid >> 6, lane = tid & 63;
  const int quad = lane >> 4, lr = lane & 15;
  const int wm   = w >> 1,  wn = w & 1;            // 2m x 2n (64m x 32n)

  const bf16_t* asrc0; const bf16_t* asrc1;
  int arow0, arow1;
  {
    const int r0 = 0*64 + w*16 + (lane >> 2);
    const int r1 = 1*64 + w*16 + (lane >> 2);
    const int s0 = segswz(lane & 3, r0);
    const int s1 = segswz(lane & 3, r1);
    int e0 = m0 + r0; if (e0 > nt-1) e0 = nt-1;
    int e1 = m0 + r1; if (e1 > nt-1) e1 = nt-1;
    asrc0 = act + (size_t)(off + e0)*FDIM + kbeg + s0*8;
    asrc1 = act + (size_t)(off + e1)*FDIM + kbeg + s1*8;
    arow0 = (0*64 + w*16)*32;
    arow1 = (1*64 + w*16)*32;
  }

  // B staging: thread t -> row t>>2 (0..63), seg t&3
  const int br = tid >> 2, bs = tid & 3;
  const float* bsrc = w2 + ((size_t)e*HDIM + (size_t)(n0 + br))*FDIM + kbeg + bs*8;
  const int bofs = br*32 + (segswz(bs, br) << 3);

  int aoff[4], boff[2];
  #pragma unroll
  for (int i = 0; i < 4; i++) {
    const int r = wm*64 + i*16 + lr;
    aoff[i] = r*32 + (segswz(quad, r) << 3);
  }
  #pragma unroll
  for (int j = 0; j < 2; j++) {
    const int r = wn*32 + j*16 + lr;
    boff[j] = r*32 + (segswz(quad, r) << 3);
  }

  f32x4 acc[4][2] = {};
  float4 b4[2][2];               // depth-2 ping-pong B regs

#define G2_LOADB(SET, K0)                                                     \
  { const float4* p_ = (const float4*)(bsrc + (K0));                          \
    b4[SET][0]=p_[0]; b4[SET][1]=p_[1]; }

#define G2_WRITEB(NXT, SET)                                                   \
  { *(bf16x8*)&Bs[NXT][bofs] = cvt8(b4[SET][0], b4[SET][1]); }

#define G2_MFMA(CUR)                                                          \
  { bf16x8 af[4], bfr[2];                                                     \
    _Pragma("unroll")                                                         \
    for (int i = 0; i < 4; i++) af[i] = *(const bf16x8*)&As[CUR][aoff[i]];    \
    _Pragma("unroll")                                                         \
    for (int j = 0; j < 2; j++) bfr[j] = *(const bf16x8*)&Bs[CUR][boff[j]];   \
    _Pragma("unroll")                                                         \
    for (int i = 0; i < 4; i++)                                               \
      _Pragma("unroll")                                                       \
      for (int j = 0; j < 2; j++)                                             \
        acc[i][j] = __builtin_amdgcn_mfma_f32_16x16x32_bf16(af[i], bfr[j], acc[i][j], 0, 0, 0); }

  // ---- prologue ----
  G2_LOADB(0, 0);                                // B(0) -> set0, 2 vm
  __builtin_amdgcn_sched_barrier(0);
  gload16(asrc0 + 0, &As[0][arow0]);             // A(0), 2 vm
  gload16(asrc1 + 0, &As[0][arow1]);
  __builtin_amdgcn_sched_barrier(0);
  G2_WRITEB(0, 0);                               // compiler drains B(0) regs
  G2_LOADB(0, 32);                               // B(1) -> set0
  G2_LOADB(1, 64);                               // B(2) -> set1
  asm volatile("s_waitcnt vmcnt(4) lgkmcnt(0)" ::: "memory");  // A(0) done
  __builtin_amdgcn_sched_barrier(0);
  __builtin_amdgcn_s_barrier();
  __builtin_amdgcn_sched_barrier(0);

#define G2_STEP(CUR, SET)                                                     \
  { G2_WRITEB((CUR)^1, SET);                                                  \
    __builtin_amdgcn_sched_barrier(0);                                        \
    gload16(asrc0 + k0 + 32, &As[(CUR)^1][arow0]);                            \
    gload16(asrc1 + k0 + 32, &As[(CUR)^1][arow1]);                            \
    __builtin_amdgcn_sched_barrier(0);                                        \
    G2_LOADB(SET, k0 + 96);                                                   \
    __builtin_amdgcn_sched_barrier(0);                                        \
    G2_MFMA(CUR);                                                             \
    asm volatile("s_waitcnt vmcnt(2) lgkmcnt(0)" ::: "memory");               \
    __builtin_amdgcn_sched_barrier(0);                                        \
    __builtin_amdgcn_s_barrier();                                             \
    __builtin_amdgcn_sched_barrier(0);                                        \
    k0 += 32; }

  int k0 = 0;
  while (k0 < 384) {              // t = 0..11 (pairs)
    G2_STEP(0, 0);
    G2_STEP(1, 1);
  }
  G2_STEP(0, 0);                  // t = 12: loads B(15) at k0+96 = 480
  // t = 13 (CUR = 1): write B(14) from set1, stage A(14)
  G2_WRITEB(0, 1);
  __builtin_amdgcn_sched_barrier(0);
  gload16(asrc0 + 448, &As[0][arow0]);
  gload16(asrc1 + 448, &As[0][arow1]);
  __builtin_amdgcn_sched_barrier(0);
  G2_MFMA(1);
  asm volatile("s_waitcnt vmcnt(0) lgkmcnt(0)" ::: "memory");
  __builtin_amdgcn_sched_barrier(0);
  __builtin_amdgcn_s_barrier();
  __builtin_amdgcn_sched_barrier(0);
  // t = 14 (CUR = 0): write B(15) from set0, stage A(15)
  G2_WRITEB(1, 0);
  __builtin_amdgcn_sched_barrier(0);
  gload16(asrc0 + 480, &As[1][arow0]);
  gload16(asrc1 + 480, &As[1][arow1]);
  __builtin_amdgcn_sched_barrier(0);
  G2_MFMA(0);
  asm volatile("s_waitcnt vmcnt(0) lgkmcnt(0)" ::: "memory");
  __builtin_amdgcn_sched_barrier(0);
  __builtin_amdgcn_s_barrier();
  __builtin_amdgcn_sched_barrier(0);
  // t = 15
  G2_MFMA(1);

#undef G2_STEP
#undef G2_MFMA
#undef G2_WRITEB
#undef G2_LOADB

  // epilogue: + b2 (k-chunk 0 only), scale, atomic scatter-add
  #pragma unroll
  for (int i = 0; i < 4; i++) {
    #pragma unroll
    for (int r = 0; r < 4; r++) {
      const int m = wm*64 + i*16 + quad*4 + r;
      if (m0 + m < nt) {
        const int slot = off + m0 + m;
        const int t    = etok[slot];
        const float s  = escale[slot];
        #pragma unroll
        for (int j = 0; j < 2; j++) {
          const int n = n0 + wn*32 + j*16 + lr;
          float v = acc[i][j][r];
          if (kc == 0) v += b2[e*HDIM + n];
          atomicAdd(&out[(size_t)t*HDIM + n], s * v);
        }
      }
    }
  }
}

extern "C" void kernel_launch(void* const* d_in, const int* in_sizes, int n_in,
                              void* d_out, int out_size, void* d_ws, size_t ws_size,
                              hipStream_t stream) {
  const float* hidden = (const float*)d_in[0];
  const int*   sel    = (const int*)d_in[1];
  const float* scal   = (const float*)d_in[2];
  const float* w1     = (const float*)d_in[3];
  const float* b1     = (const float*)d_in[4];
  const float* w2     = (const float*)d_in[5];
  const float* b2     = (const float*)d_in[6];
  float* out = (float*)d_out;

  char* ws = (char*)d_ws;
  int*    offsets = (int*)(ws + WB_OFFSETS);
  int*    etok    = (int*)(ws + WB_ETOK);
  float*  escale  = (float*)(ws + WB_ESCALE);
  bf16_t* act     = (bf16_t*)(ws + WB_ACT);
  bf16_t* hbf     = (bf16_t*)(ws + WB_H);

  hipMemsetAsync(d_out, 0, (size_t)out_size * sizeof(float), stream);

  route_all<<<1, 256, 0, stream>>>(sel, scal, offsets, etok, escale);
  convert_h<<<(int)(H_ELEMS/8/256), 256, 0, stream>>>(hidden, hbf);

  // gemm1: x = n-tile (64, BN=32), y = expert, z = m-tile -> 1024 live blocks.
  gemm1_v13<<<dim3(FDIM/32, NEXP, NENT/128), 256, 0, stream>>>(hbf, w1, b1, offsets, etok, act);
  // gemm2: x = n-tile(16, BN=64) x splitK(4), y = expert, z = m-tile -> 1024 live.
  gemm2_v13<<<dim3((HDIM/64)*4, NEXP, NENT/128), 256, 0, stream>>>(act, w2, b2, offsets, etok, escale, out);
}